// Round 5
// baseline (545.660 us; speedup 1.0000x reference)
//
#include <hip/hip_runtime.h>

#define BB     2048
#define TT     512
#define INDIM  28
#define HH     64
#define NC     10
#define ROWS   8
#define NTHREADS 256
#define LDA    72    // halfs per A row (h-only tile): 144 B stride -> 2-way bank alias (free), rows 16B-aligned

typedef __attribute__((ext_vector_type(8))) _Float16 f16x8;
typedef __attribute__((ext_vector_type(4))) float     f32x4;

__device__ __forceinline__ float frcp(float v)  { return __builtin_amdgcn_rcpf(v); }
__device__ __forceinline__ float fsig(float v)  { return frcp(1.f + __expf(-v)); }
__device__ __forceinline__ float ftanh_(float v){ return fmaf(-2.f, frcp(1.f + __expf(2.f*v)), 1.f); }

#define MFMA(A_, B_, C_) __builtin_amdgcn_mfma_f32_16x16x32_f16((A_), (B_), (C_), 0, 0, 0)

// LDS-only barrier: orders our ds_writes (lgkmcnt(0)) then syncs. Unlike __syncthreads(),
// does NOT drain vmcnt -> the per-step x global_load stays in flight across the barrier
// (it's lane-private, consumed by the same thread one iteration later: no cross-wave
// visibility needed, so this is memory-model sound).
__device__ __forceinline__ void lds_barrier() {
    asm volatile("s_waitcnt lgkmcnt(0)" ::: "memory");
    __builtin_amdgcn_s_barrier();
}

// A-tile (16 x 96): rows 0-7 = h_hi, rows 8-15 = h_lo of the block's 8 batch rows
// (k=0..63 from LDS); k=64..95 is the x part, built per-lane IN REGISTERS from
// prefetched global loads (never staged in LDS). Two MFMAs per tile-kstep (B_hi, B_lo)
// -> hi*(hi+lo) in C-rows 0-7, lo*(hi+lo) in C-rows 8-15; one __shfl_xor(32) combines.
// Wave w's 4 C-tiles = gates [r, z, n_h, n_x] for units 16w..16w+15: gate math in-lane.
extern "C" __global__ __launch_bounds__(NTHREADS, 1)
void gru_mfma(const float* __restrict__ x,
              const float* __restrict__ W_ih,
              const float* __restrict__ W_hh,
              const float* __restrict__ b_ih,
              const float* __restrict__ b_hh,
              const float* __restrict__ W_out,
              const float* __restrict__ b_out,
              float* __restrict__ out)
{
    __shared__ __align__(16) _Float16 A_[2][16][LDA];
    __shared__ float hs_f[ROWS][HH];
    __shared__ float lg[ROWS][NC];

    const int tid = threadIdx.x;
    const int w   = tid >> 6;
    const int l   = tid & 63;
    const int c   = l & 15;          // A row sel / B col / C col
    const int hi  = l >> 4;          // lane quad
    const int hi8 = hi * 8;
    const int u   = w * 16 + c;      // hidden unit for this lane's gates
    const int r0  = blockIdx.x * ROWS;

    // ---- B fragments (weights), hi/lo fp16, register-resident ----
    // frag f -> (gate g, kstep s): 0..2:(r,s) 3..5:(z,s) 6..7:(nh,0/1) 8:(nx,2)
    f16x8 Bh[9], Bl[9];
    {
        const int GS[9][2] = {{0,0},{0,1},{0,2},{1,0},{1,1},{1,2},{2,0},{2,1},{3,2}};
        #pragma unroll
        for (int f = 0; f < 9; ++f) {
            const int g = GS[f][0], s = GS[f][1];
            #pragma unroll
            for (int j = 0; j < 8; ++j) {
                const int k = s * 32 + hi8 + j;
                float v = 0.f;
                if (g == 2)      { if (k < 64) v = W_hh[(size_t)(u + 128) * HH + k]; }
                else if (g == 3) { if (k >= 64 && k < 64 + INDIM) v = W_ih[(size_t)(u + 128) * INDIM + (k - 64)]; }
                else {
                    const int ru = u + 64 * g;
                    if (k < 64)              v = W_hh[(size_t)ru * HH + k];
                    else if (k < 64 + INDIM) v = W_ih[(size_t)ru * INDIM + (k - 64)];
                }
                const _Float16 vh = (_Float16)v;
                Bh[f][j] = vh;
                Bl[f][j] = (_Float16)(v - (float)vh);
            }
        }
    }
    const float bs0  = b_ih[u]       + b_hh[u];        // r-gate bias
    const float bs1  = b_ih[u + 64]  + b_hh[u + 64];   // z-gate bias
    const float bihn = b_ih[u + 128];                  // n-gate x bias
    const float bhhn = b_hh[u + 128];                  // n-gate h bias (inside r*(...))

    // ---- zero both A buffers (h starts at 0; pad cols 64..71 stay 0) ----
    for (int i = tid; i < 2 * 16 * LDA; i += NTHREADS) ((_Float16*)A_)[i] = (_Float16)0.f;

    // lane-private x pointer: row (c&7), col base hi8 (cols hi8..hi8+7 of INDIM=28)
    const float* xlane = x + (size_t)(r0 + (c & 7)) * TT * INDIM + hi8;
    float4 xa = *(const float4*)xlane;                                  // t=0
    float4 xb = (hi < 3) ? *(const float4*)(xlane + 4) : float4{0,0,0,0};
    __syncthreads();

    float h[4] = {0.f, 0.f, 0.f, 0.f};   // batch row 4*(hi&1)+i
    int p = 0;

    for (int t = 0; t < TT; ++t) {
        // issue next-step x loads; they stay in flight across the (LDS-only) barrier
        float4 na = {0,0,0,0}, nb = {0,0,0,0};
        if (t + 1 < TT) {
            const float* xp = xlane + (size_t)(t + 1) * INDIM;
            na = *(const float4*)xp;
            if (hi < 3) nb = *(const float4*)(xp + 4);
        }

        // h fragments from LDS
        const f16x8 af0 = *(const f16x8*)&A_[p][c][hi8];
        const f16x8 af1 = *(const f16x8*)&A_[p][c][32 + hi8];

        // x fragment built in registers (c<8: hi part; c>=8: lo residual)
        f16x8 af2;
        {
            const float v[8] = {xa.x, xa.y, xa.z, xa.w, xb.x, xb.y, xb.z, xb.w};
            #pragma unroll
            for (int j = 0; j < 8; ++j) {
                const _Float16 vh = (_Float16)v[j];
                af2[j] = (c >= 8) ? (_Float16)(v[j] - (float)vh) : vh;
            }
        }

        f32x4 acc[4] = {{0,0,0,0},{0,0,0,0},{0,0,0,0},{0,0,0,0}};
        // k-step 0 (h units 0..31)
        acc[0] = MFMA(af0, Bh[0], acc[0]); acc[0] = MFMA(af0, Bl[0], acc[0]);
        acc[1] = MFMA(af0, Bh[3], acc[1]); acc[1] = MFMA(af0, Bl[3], acc[1]);
        acc[2] = MFMA(af0, Bh[6], acc[2]); acc[2] = MFMA(af0, Bl[6], acc[2]);
        // k-step 1 (h units 32..63)
        acc[0] = MFMA(af1, Bh[1], acc[0]); acc[0] = MFMA(af1, Bl[1], acc[0]);
        acc[1] = MFMA(af1, Bh[4], acc[1]); acc[1] = MFMA(af1, Bl[4], acc[1]);
        acc[2] = MFMA(af1, Bh[7], acc[2]); acc[2] = MFMA(af1, Bl[7], acc[2]);
        // k-step 2 (x)
        acc[0] = MFMA(af2, Bh[2], acc[0]); acc[0] = MFMA(af2, Bl[2], acc[0]);
        acc[1] = MFMA(af2, Bh[5], acc[1]); acc[1] = MFMA(af2, Bl[5], acc[1]);
        acc[3] = MFMA(af2, Bh[8], acc[3]); acc[3] = MFMA(af2, Bl[8], acc[3]);

        // combine hi-rows (C rows 0-7) with lo-rows (C rows 8-15): lane xor 32
        #pragma unroll
        for (int g = 0; g < 4; ++g)
            #pragma unroll
            for (int i = 0; i < 4; ++i)
                acc[g][i] += __shfl_xor(acc[g][i], 32);

        // gate math fully in-lane (hi>=2 lanes are exact duplicates, produce the lo part)
        #pragma unroll
        for (int i = 0; i < 4; ++i) {
            const float rg = fsig(acc[0][i] + bs0);
            const float zg = fsig(acc[1][i] + bs1);
            const float ng = ftanh_(acc[3][i] + bihn + rg * (acc[2][i] + bhhn));
            h[i] = fmaf(zg, h[i] - ng, ng);          // (1-z)*n + z*h
        }
        // write h_{t+1}: A-row = 4*hi+i; hi<2 write hi-part, hi>=2 write lo-part
        #pragma unroll
        for (int i = 0; i < 4; ++i) {
            const _Float16 vh = (_Float16)h[i];
            const _Float16 vl = (_Float16)(h[i] - (float)vh);
            A_[p ^ 1][4 * hi + i][u] = (hi >= 2) ? vl : vh;
        }
        lds_barrier();            // LDS-only: x loads stay outstanding
        xa = na; xb = nb;
        p ^= 1;
    }

    // ---- epilogue: logits + softmax for this block's 8 rows ----
    if (hi < 2) {
        #pragma unroll
        for (int i = 0; i < 4; ++i) hs_f[4 * hi + i][u] = h[i];
    }
    __syncthreads();
    if (tid < ROWS * NC) {
        const int rr = tid / NC, cc = tid % NC;
        float s = b_out[cc];
        const float* wo = W_out + (size_t)cc * HH;
        #pragma unroll
        for (int j = 0; j < HH; ++j) s = fmaf(wo[j], hs_f[rr][j], s);
        lg[rr][cc] = s;
    }
    __syncthreads();
    if (tid < ROWS) {
        float mx = -1e30f;
        #pragma unroll
        for (int cc = 0; cc < NC; ++cc) mx = fmaxf(mx, lg[tid][cc]);
        float e[NC]; float ssum = 0.f;
        #pragma unroll
        for (int cc = 0; cc < NC; ++cc) { e[cc] = __expf(lg[tid][cc] - mx); ssum += e[cc]; }
        const float inv = 1.f / ssum;
        float* op = out + (size_t)(r0 + tid) * NC;
        #pragma unroll
        for (int cc = 0; cc < NC; ++cc) op[cc] = e[cc] * inv;
    }
}

extern "C" void kernel_launch(void* const* d_in, const int* in_sizes, int n_in,
                              void* d_out, int out_size, void* d_ws, size_t ws_size,
                              hipStream_t stream) {
    const float* x     = (const float*)d_in[0];
    const float* W_ih  = (const float*)d_in[1];
    const float* W_hh  = (const float*)d_in[2];
    const float* b_ih  = (const float*)d_in[3];
    const float* b_hh  = (const float*)d_in[4];
    const float* W_out = (const float*)d_in[5];
    const float* b_out = (const float*)d_in[6];
    (void)in_sizes; (void)n_in; (void)d_ws; (void)ws_size; (void)out_size;

    gru_mfma<<<BB / ROWS, NTHREADS, 0, stream>>>(x, W_ih, W_hh, b_ih, b_hh,
                                                 W_out, b_out, (float*)d_out);
}

// Round 7
// 342.491 us; speedup vs baseline: 1.5932x; 1.5932x over previous
//
#include <hip/hip_runtime.h>

#define BB     2048
#define TT     512
#define INDIM  28
#define HH     64
#define NC     10
#define ROWS   8
#define NTHREADS 256
#define LDA    104   // halfs per A row: 208 B -> rows 16B-aligned, 2-way bank alias max (free)

typedef __attribute__((ext_vector_type(8))) _Float16 f16x8;
typedef __attribute__((ext_vector_type(4))) float     f32x4;

__device__ __forceinline__ float frcp(float v)  { return __builtin_amdgcn_rcpf(v); }
__device__ __forceinline__ float fsig(float v)  { return frcp(1.f + __expf(-v)); }
__device__ __forceinline__ float ftanh_(float v){ return fmaf(-2.f, frcp(1.f + __expf(2.f*v)), 1.f); }

#define MFMA(A_, B_, C_) __builtin_amdgcn_mfma_f32_16x16x32_f16((A_), (B_), (C_), 0, 0, 0)

// LDS-only barrier: orders our ds_writes (lgkmcnt(0)) then syncs. Does NOT drain vmcnt,
// so the deep-prefetched x global loads stay in flight across step boundaries.
__device__ __forceinline__ void lds_barrier() {
    asm volatile("s_waitcnt lgkmcnt(0)" ::: "memory");
    __builtin_amdgcn_s_barrier();
}

// Bit-exact round-4 numerics: A-tile rows 0-7 = [h_hi|x_hi], rows 8-15 = [h_lo|x_lo];
// per tile-kstep acc = MFMA(af,Bh,acc); acc = MFMA(af,Bl,acc) (single chain), then
// acc += __shfl_xor(acc,32). Only scheduling differs from round 4:
//  (a) x is prefetched 8 steps deep (group-unrolled, compile-time indices),
//  (b) per-step barrier is LDS-only (no vmcnt drain), keeping those loads in flight.
extern "C" __global__ __launch_bounds__(NTHREADS, 1)
void gru_mfma(const float* __restrict__ x,
              const float* __restrict__ W_ih,
              const float* __restrict__ W_hh,
              const float* __restrict__ b_ih,
              const float* __restrict__ b_hh,
              const float* __restrict__ W_out,
              const float* __restrict__ b_out,
              float* __restrict__ out)
{
    __shared__ __align__(16) _Float16 A_[2][16][LDA];
    __shared__ float hs_f[ROWS][HH];
    __shared__ float lg[ROWS][NC];

    const int tid = threadIdx.x;
    const int w   = tid >> 6;
    const int l   = tid & 63;
    const int c   = l & 15;          // A row sel / B col / C col
    const int hi  = l >> 4;          // lane quad
    const int hi8 = hi * 8;
    const int u   = w * 16 + c;      // hidden unit for this lane's gates
    const int r0  = blockIdx.x * ROWS;

    // ---- B fragments (weights), hi/lo fp16, register-resident ----
    // frag f -> (gate g, kstep s): 0..2:(r,s) 3..5:(z,s) 6..7:(nh,0/1) 8:(nx,2)
    f16x8 Bh[9], Bl[9];
    {
        const int GS[9][2] = {{0,0},{0,1},{0,2},{1,0},{1,1},{1,2},{2,0},{2,1},{3,2}};
        #pragma unroll
        for (int f = 0; f < 9; ++f) {
            const int g = GS[f][0], s = GS[f][1];
            #pragma unroll
            for (int j = 0; j < 8; ++j) {
                const int k = s * 32 + hi8 + j;
                float v = 0.f;
                if (g == 2)      { if (k < 64) v = W_hh[(size_t)(u + 128) * HH + k]; }
                else if (g == 3) { if (k >= 64 && k < 64 + INDIM) v = W_ih[(size_t)(u + 128) * INDIM + (k - 64)]; }
                else {
                    const int ru = u + 64 * g;
                    if (k < 64)              v = W_hh[(size_t)ru * HH + k];
                    else if (k < 64 + INDIM) v = W_ih[(size_t)ru * INDIM + (k - 64)];
                }
                const _Float16 vh = (_Float16)v;
                Bh[f][j] = vh;
                Bl[f][j] = (_Float16)(v - (float)vh);
            }
        }
    }
    const float bs0  = b_ih[u]       + b_hh[u];        // r-gate bias
    const float bs1  = b_ih[u + 64]  + b_hh[u + 64];   // z-gate bias
    const float bihn = b_ih[u + 128];                  // n-gate x bias
    const float bhhn = b_hh[u + 128];                  // n-gate h bias (inside r*(...))

    // ---- zero both A buffers ----
    for (int i = tid; i < 2 * 16 * LDA; i += NTHREADS) ((_Float16*)A_)[i] = (_Float16)0.f;
    // stage x_0 (hi -> rows 0-7, lo -> rows 8-15); coalesced 224-thread path
    const int  act = (tid < ROWS * INDIM);
    const int  xr  = tid / INDIM, xi = tid % INDIM;
    const float* xbase = x + (size_t)(r0 + (act ? xr : 0)) * TT * INDIM + xi;
    if (act) {
        const float v = xbase[0];
        const _Float16 vh = (_Float16)v;
        A_[0][xr    ][64 + xi] = vh;
        A_[0][xr + 8][64 + xi] = (_Float16)(v - (float)vh);
    }
    // prefetch group 0's x: steps 1..8
    float xg[8];
    #pragma unroll
    for (int k = 0; k < 8; ++k) xg[k] = act ? xbase[(size_t)(1 + k) * INDIM] : 0.f;
    __syncthreads();

    float h[4] = {0.f, 0.f, 0.f, 0.f};   // batch row 4*(hi&1)+i
    int p = 0;

    for (int g = 0; g < TT / 8; ++g) {
        // issue next group's x loads (steps 8g+9 .. 8g+16); consumed >= 8 iters later
        float xn[8];
        #pragma unroll
        for (int k = 0; k < 8; ++k) {
            const int st = 8 * (g + 1) + 1 + k;
            xn[k] = (act && st < TT) ? xbase[(size_t)st * INDIM] : 0.f;
        }

        #pragma unroll
        for (int k = 0; k < 8; ++k) {
            const int t = 8 * g + k;

            const f16x8 af0 = *(const f16x8*)&A_[p][c][hi8];
            const f16x8 af1 = *(const f16x8*)&A_[p][c][32 + hi8];
            const f16x8 af2 = *(const f16x8*)&A_[p][c][64 + hi8];

            f32x4 acc[4] = {{0,0,0,0},{0,0,0,0},{0,0,0,0},{0,0,0,0}};
            // k-step 0 (h units 0..31)
            acc[0] = MFMA(af0, Bh[0], acc[0]); acc[0] = MFMA(af0, Bl[0], acc[0]);
            acc[1] = MFMA(af0, Bh[3], acc[1]); acc[1] = MFMA(af0, Bl[3], acc[1]);
            acc[2] = MFMA(af0, Bh[6], acc[2]); acc[2] = MFMA(af0, Bl[6], acc[2]);
            // k-step 1 (h units 32..63)
            acc[0] = MFMA(af1, Bh[1], acc[0]); acc[0] = MFMA(af1, Bl[1], acc[0]);
            acc[1] = MFMA(af1, Bh[4], acc[1]); acc[1] = MFMA(af1, Bl[4], acc[1]);
            acc[2] = MFMA(af1, Bh[7], acc[2]); acc[2] = MFMA(af1, Bl[7], acc[2]);
            // k-step 2 (x)
            acc[0] = MFMA(af2, Bh[2], acc[0]); acc[0] = MFMA(af2, Bl[2], acc[0]);
            acc[1] = MFMA(af2, Bh[5], acc[1]); acc[1] = MFMA(af2, Bl[5], acc[1]);
            acc[3] = MFMA(af2, Bh[8], acc[3]); acc[3] = MFMA(af2, Bl[8], acc[3]);

            // combine hi-rows with lo-rows (lane xor 32) — round-4 exact
            #pragma unroll
            for (int gg = 0; gg < 4; ++gg)
                #pragma unroll
                for (int i = 0; i < 4; ++i)
                    acc[gg][i] += __shfl_xor(acc[gg][i], 32);

            // gate math fully in-lane
            #pragma unroll
            for (int i = 0; i < 4; ++i) {
                const float rg = fsig(acc[0][i] + bs0);
                const float zg = fsig(acc[1][i] + bs1);
                const float ng = ftanh_(acc[3][i] + bihn + rg * (acc[2][i] + bhhn));
                h[i] = fmaf(zg, h[i] - ng, ng);      // (1-z)*n + z*h
            }
            // write h_{t+1}: A-row = 4*hi+i; hi<2 hi-part, hi>=2 lo-part
            #pragma unroll
            for (int i = 0; i < 4; ++i) {
                const _Float16 vh = (_Float16)h[i];
                const _Float16 vl = (_Float16)(h[i] - (float)vh);
                A_[p ^ 1][4 * hi + i][u] = (hi >= 2) ? vl : vh;
            }
            // write x_{t+1} from the 8-deep prefetch (load completed long ago)
            if (act && t + 1 < TT) {
                const float xv = xg[k];
                const _Float16 vh = (_Float16)xv;
                A_[p ^ 1][xr    ][64 + xi] = vh;
                A_[p ^ 1][xr + 8][64 + xi] = (_Float16)(xv - (float)vh);
            }
            lds_barrier();
            p ^= 1;
        }
        #pragma unroll
        for (int k = 0; k < 8; ++k) xg[k] = xn[k];
    }

    // ---- epilogue: logits + softmax for this block's 8 rows ----
    if (hi < 2) {
        #pragma unroll
        for (int i = 0; i < 4; ++i) hs_f[4 * hi + i][u] = h[i];
    }
    __syncthreads();
    if (tid < ROWS * NC) {
        const int rr = tid / NC, cc = tid % NC;
        float s = b_out[cc];
        const float* wo = W_out + (size_t)cc * HH;
        #pragma unroll
        for (int j = 0; j < HH; ++j) s = fmaf(wo[j], hs_f[rr][j], s);
        lg[rr][cc] = s;
    }
    __syncthreads();
    if (tid < ROWS) {
        float mx = -1e30f;
        #pragma unroll
        for (int cc = 0; cc < NC; ++cc) mx = fmaxf(mx, lg[tid][cc]);
        float e[NC]; float ssum = 0.f;
        #pragma unroll
        for (int cc = 0; cc < NC; ++cc) { e[cc] = __expf(lg[tid][cc] - mx); ssum += e[cc]; }
        const float inv = 1.f / ssum;
        float* op = out + (size_t)(r0 + tid) * NC;
        #pragma unroll
        for (int cc = 0; cc < NC; ++cc) op[cc] = e[cc] * inv;
    }
}

extern "C" void kernel_launch(void* const* d_in, const int* in_sizes, int n_in,
                              void* d_out, int out_size, void* d_ws, size_t ws_size,
                              hipStream_t stream) {
    const float* x     = (const float*)d_in[0];
    const float* W_ih  = (const float*)d_in[1];
    const float* W_hh  = (const float*)d_in[2];
    const float* b_ih  = (const float*)d_in[3];
    const float* b_hh  = (const float*)d_in[4];
    const float* W_out = (const float*)d_in[5];
    const float* b_out = (const float*)d_in[6];
    (void)in_sizes; (void)n_in; (void)d_ws; (void)ws_size; (void)out_size;

    gru_mfma<<<BB / ROWS, NTHREADS, 0, stream>>>(x, W_ih, W_hh, b_ih, b_hh,
                                                 W_out, b_out, (float*)d_out);
}

// Round 8
// 336.649 us; speedup vs baseline: 1.6209x; 1.0174x over previous
//
#include <hip/hip_runtime.h>

#define BB     2048
#define TT     512
#define INDIM  28
#define HH     64
#define NC     10
#define ROWS   8
#define NTHREADS 256
#define LDA    104   // halfs per A row: 208 B -> rows 16B-aligned, 2-way bank alias max (free)

typedef __attribute__((ext_vector_type(8))) _Float16 f16x8;
typedef __attribute__((ext_vector_type(4))) float     f32x4;
typedef __attribute__((ext_vector_type(2))) unsigned int uint2v;

__device__ __forceinline__ float frcp(float v)  { return __builtin_amdgcn_rcpf(v); }
__device__ __forceinline__ float fsig(float v)  { return frcp(1.f + __expf(-v)); }
__device__ __forceinline__ float ftanh_(float v){ return fmaf(-2.f, frcp(1.f + __expf(2.f*v)), 1.f); }

#define MFMA(A_, B_, C_) __builtin_amdgcn_mfma_f32_16x16x32_f16((A_), (B_), (C_), 0, 0, 0)

// s + s[lane^32] on the VALU via the verified builtin (T12). Value semantics: the
// compiler materializes distinct registers, so no self-swap aliasing (round-6 bug).
// swap(a=s, b=s): r.x = l<32 ? s[l+32] : s[l]; r.y = l<32 ? s[l] : s[l-32]; sum = both.
__device__ __forceinline__ float xor32_sum(float s) {
    const unsigned int si = __float_as_uint(s);
    const uint2v r = __builtin_amdgcn_permlane32_swap(si, si, false, false);
    return __uint_as_float(r.x) + __uint_as_float(r.y);
}

// LDS-only barrier: orders our ds_writes (lgkmcnt(0)) then syncs. Does NOT drain vmcnt,
// so the deep-prefetched x global loads stay in flight across step boundaries.
__device__ __forceinline__ void lds_barrier() {
    asm volatile("s_waitcnt lgkmcnt(0)" ::: "memory");
    __builtin_amdgcn_s_barrier();
}

// A-tile (16 x 96): rows 0-7 = [h_hi|x_hi], rows 8-15 = [h_lo|x_lo] of the block's
// 8 batch rows. Per tile-kstep: MFMA vs B_hi into aH, vs B_lo into aL (two depth-3
// chains instead of one depth-6). hi*(hi+lo) lands in C-rows 0-7, lo*(hi+lo) in rows
// 8-15; combine = (aH+aL) + permlane32_swap sum -> full (hi+lo)x(hi+lo) per lane.
// Wave w's 4 C-tiles = gates [r, z, n_h, n_x] for units 16w..16w+15: gate math in-lane.
// x: prefetched 8 steps deep (compile-time indices), consumed by pre-barrier ds_write.
extern "C" __global__ __launch_bounds__(NTHREADS, 1)
void gru_mfma(const float* __restrict__ x,
              const float* __restrict__ W_ih,
              const float* __restrict__ W_hh,
              const float* __restrict__ b_ih,
              const float* __restrict__ b_hh,
              const float* __restrict__ W_out,
              const float* __restrict__ b_out,
              float* __restrict__ out)
{
    __shared__ __align__(16) _Float16 A_[2][16][LDA];
    __shared__ float hs_f[ROWS][HH];
    __shared__ float lg[ROWS][NC];

    const int tid = threadIdx.x;
    const int w   = tid >> 6;
    const int l   = tid & 63;
    const int c   = l & 15;          // A row sel / B col / C col
    const int hi  = l >> 4;          // lane quad
    const int hi8 = hi * 8;
    const int u   = w * 16 + c;      // hidden unit for this lane's gates
    const int r0  = blockIdx.x * ROWS;

    // ---- B fragments (weights), hi/lo fp16, register-resident ----
    // frag f -> (gate g, kstep s): 0..2:(r,s) 3..5:(z,s) 6..7:(nh,0/1) 8:(nx,2)
    f16x8 Bh[9], Bl[9];
    {
        const int GS[9][2] = {{0,0},{0,1},{0,2},{1,0},{1,1},{1,2},{2,0},{2,1},{3,2}};
        #pragma unroll
        for (int f = 0; f < 9; ++f) {
            const int g = GS[f][0], s = GS[f][1];
            #pragma unroll
            for (int j = 0; j < 8; ++j) {
                const int k = s * 32 + hi8 + j;
                float v = 0.f;
                if (g == 2)      { if (k < 64) v = W_hh[(size_t)(u + 128) * HH + k]; }
                else if (g == 3) { if (k >= 64 && k < 64 + INDIM) v = W_ih[(size_t)(u + 128) * INDIM + (k - 64)]; }
                else {
                    const int ru = u + 64 * g;
                    if (k < 64)              v = W_hh[(size_t)ru * HH + k];
                    else if (k < 64 + INDIM) v = W_ih[(size_t)ru * INDIM + (k - 64)];
                }
                const _Float16 vh = (_Float16)v;
                Bh[f][j] = vh;
                Bl[f][j] = (_Float16)(v - (float)vh);
            }
        }
    }
    const float bs0  = b_ih[u]       + b_hh[u];        // r-gate bias
    const float bs1  = b_ih[u + 64]  + b_hh[u + 64];   // z-gate bias
    const float bihn = b_ih[u + 128];                  // n-gate x bias
    const float bhhn = b_hh[u + 128];                  // n-gate h bias (inside r*(...))

    // ---- zero both A buffers ----
    for (int i = tid; i < 2 * 16 * LDA; i += NTHREADS) ((_Float16*)A_)[i] = (_Float16)0.f;
    // stage x_0 (hi -> rows 0-7, lo -> rows 8-15); coalesced 224-thread path
    const int  act = (tid < ROWS * INDIM);
    const int  xr  = tid / INDIM, xi = tid % INDIM;
    const float* xbase = x + (size_t)(r0 + (act ? xr : 0)) * TT * INDIM + xi;
    if (act) {
        const float v = xbase[0];
        const _Float16 vh = (_Float16)v;
        A_[0][xr    ][64 + xi] = vh;
        A_[0][xr + 8][64 + xi] = (_Float16)(v - (float)vh);
    }
    // prefetch group 0's x: steps 1..8
    float xg[8];
    #pragma unroll
    for (int k = 0; k < 8; ++k) xg[k] = act ? xbase[(size_t)(1 + k) * INDIM] : 0.f;
    __syncthreads();

    float h[4] = {0.f, 0.f, 0.f, 0.f};   // batch row 4*(hi&1)+i
    int p = 0;

    for (int g = 0; g < TT / 8; ++g) {
        // issue next group's x loads (steps 8g+9 .. 8g+16); consumed >= 8 iters later
        float xn[8];
        #pragma unroll
        for (int k = 0; k < 8; ++k) {
            const int st = 8 * (g + 1) + 1 + k;
            xn[k] = (act && st < TT) ? xbase[(size_t)st * INDIM] : 0.f;
        }

        #pragma unroll
        for (int k = 0; k < 8; ++k) {
            const int t = 8 * g + k;

            const f16x8 af0 = *(const f16x8*)&A_[p][c][hi8];
            const f16x8 af1 = *(const f16x8*)&A_[p][c][32 + hi8];
            const f16x8 af2 = *(const f16x8*)&A_[p][c][64 + hi8];

            f32x4 aH[4] = {{0,0,0,0},{0,0,0,0},{0,0,0,0},{0,0,0,0}};
            f32x4 aL[4] = {{0,0,0,0},{0,0,0,0},{0,0,0,0},{0,0,0,0}};
            // k-step 0 (h units 0..31)
            aH[0] = MFMA(af0, Bh[0], aH[0]);  aL[0] = MFMA(af0, Bl[0], aL[0]);
            aH[1] = MFMA(af0, Bh[3], aH[1]);  aL[1] = MFMA(af0, Bl[3], aL[1]);
            aH[2] = MFMA(af0, Bh[6], aH[2]);  aL[2] = MFMA(af0, Bl[6], aL[2]);
            // k-step 1 (h units 32..63)
            aH[0] = MFMA(af1, Bh[1], aH[0]);  aL[0] = MFMA(af1, Bl[1], aL[0]);
            aH[1] = MFMA(af1, Bh[4], aH[1]);  aL[1] = MFMA(af1, Bl[4], aL[1]);
            aH[2] = MFMA(af1, Bh[7], aH[2]);  aL[2] = MFMA(af1, Bl[7], aL[2]);
            // k-step 2 (x)
            aH[0] = MFMA(af2, Bh[2], aH[0]);  aL[0] = MFMA(af2, Bl[2], aL[0]);
            aH[1] = MFMA(af2, Bh[5], aH[1]);  aL[1] = MFMA(af2, Bl[5], aL[1]);
            aH[3] = MFMA(af2, Bh[8], aH[3]);  aL[3] = MFMA(af2, Bl[8], aL[3]);

            // combine: H+L, then hi-rows + lo-rows (lane^32) on the VALU (no DS pipe)
            f32x4 acc[4];
            #pragma unroll
            for (int gg = 0; gg < 4; ++gg)
                #pragma unroll
                for (int i = 0; i < 4; ++i)
                    acc[gg][i] = xor32_sum(aH[gg][i] + aL[gg][i]);

            // gate math fully in-lane
            #pragma unroll
            for (int i = 0; i < 4; ++i) {
                const float rg = fsig(acc[0][i] + bs0);
                const float zg = fsig(acc[1][i] + bs1);
                const float ng = ftanh_(acc[3][i] + bihn + rg * (acc[2][i] + bhhn));
                h[i] = fmaf(zg, h[i] - ng, ng);      // (1-z)*n + z*h
            }
            // write h_{t+1}: A-row = 4*hi+i; hi<2 hi-part, hi>=2 lo-part
            #pragma unroll
            for (int i = 0; i < 4; ++i) {
                const _Float16 vh = (_Float16)h[i];
                const _Float16 vl = (_Float16)(h[i] - (float)vh);
                A_[p ^ 1][4 * hi + i][u] = (hi >= 2) ? vl : vh;
            }
            // write x_{t+1} from the 8-deep prefetch (load completed long ago)
            if (act && t + 1 < TT) {
                const float xv = xg[k];
                const _Float16 vh = (_Float16)xv;
                A_[p ^ 1][xr    ][64 + xi] = vh;
                A_[p ^ 1][xr + 8][64 + xi] = (_Float16)(xv - (float)vh);
            }
            lds_barrier();
            p ^= 1;
        }
        #pragma unroll
        for (int k = 0; k < 8; ++k) xg[k] = xn[k];
    }

    // ---- epilogue: logits + softmax for this block's 8 rows ----
    if (hi < 2) {
        #pragma unroll
        for (int i = 0; i < 4; ++i) hs_f[4 * hi + i][u] = h[i];
    }
    __syncthreads();
    if (tid < ROWS * NC) {
        const int rr = tid / NC, cc = tid % NC;
        float s = b_out[cc];
        const float* wo = W_out + (size_t)cc * HH;
        #pragma unroll
        for (int j = 0; j < HH; ++j) s = fmaf(wo[j], hs_f[rr][j], s);
        lg[rr][cc] = s;
    }
    __syncthreads();
    if (tid < ROWS) {
        float mx = -1e30f;
        #pragma unroll
        for (int cc = 0; cc < NC; ++cc) mx = fmaxf(mx, lg[tid][cc]);
        float e[NC]; float ssum = 0.f;
        #pragma unroll
        for (int cc = 0; cc < NC; ++cc) { e[cc] = __expf(lg[tid][cc] - mx); ssum += e[cc]; }
        const float inv = 1.f / ssum;
        float* op = out + (size_t)(r0 + tid) * NC;
        #pragma unroll
        for (int cc = 0; cc < NC; ++cc) op[cc] = e[cc] * inv;
    }
}

extern "C" void kernel_launch(void* const* d_in, const int* in_sizes, int n_in,
                              void* d_out, int out_size, void* d_ws, size_t ws_size,
                              hipStream_t stream) {
    const float* x     = (const float*)d_in[0];
    const float* W_ih  = (const float*)d_in[1];
    const float* W_hh  = (const float*)d_in[2];
    const float* b_ih  = (const float*)d_in[3];
    const float* b_hh  = (const float*)d_in[4];
    const float* W_out = (const float*)d_in[5];
    const float* b_out = (const float*)d_in[6];
    (void)in_sizes; (void)n_in; (void)d_ws; (void)ws_size; (void)out_size;

    gru_mfma<<<BB / ROWS, NTHREADS, 0, stream>>>(x, W_ih, W_hh, b_ih, b_hh,
                                                 W_out, b_out, (float*)d_out);
}

// Round 9
// 223.561 us; speedup vs baseline: 2.4408x; 1.5058x over previous
//
#include <hip/hip_runtime.h>

#define BB     2048
#define TT     512
#define INDIM  28
#define HH     64
#define NC     10
#define ROWS   16
#define NTHREADS 256
#define LDA    104   // halfs per A row: 208 B stride -> 16B-aligned rows, worst 2-way bank alias (free)

typedef __attribute__((ext_vector_type(8))) _Float16 f16x8;
typedef __attribute__((ext_vector_type(4))) float     f32x4;

__device__ __forceinline__ float frcp(float v)  { return __builtin_amdgcn_rcpf(v); }
__device__ __forceinline__ float fsig(float v)  { return frcp(1.f + __expf(-v)); }
__device__ __forceinline__ float ftanh_(float v){ return fmaf(-2.f, frcp(1.f + __expf(2.f*v)), 1.f); }

#define MFMA(A_, B_, C_) __builtin_amdgcn_mfma_f32_16x16x32_f16((A_), (B_), (C_), 0, 0, 0)

// LDS-only barrier: orders our ds_writes (lgkmcnt(0)) then syncs. Does NOT drain vmcnt,
// so the deep-prefetched x global loads stay in flight across step boundaries.
__device__ __forceinline__ void lds_barrier() {
    asm volatile("s_waitcnt lgkmcnt(0)" ::: "memory");
    __builtin_amdgcn_s_barrier();
}

// Pure-fp16 design (absmax headroom: split version measured 0.0 vs 3.4e-3 threshold):
// A-tile (16 x 96) = 16 REAL batch rows, [h f16 (k 0..63) | x f16 (k 64..91) | pad].
// 9 MFMAs/step: r,z over 3 k-steps; n_h over k-steps 0,1; n_x over k-step 2.
// C[row][col]: col = lane&15 -> unit u, row = 4*(lane>>4)+reg -> batch row. Every lane
// owns 4 distinct rows of the same unit: NO cross-lane combine at all. Gate math
// fully in-lane; h round-trips via one f16 ds_write per row. x prefetched 8 steps deep.
extern "C" __global__ __launch_bounds__(NTHREADS, 1)
void gru_mfma(const float* __restrict__ x,
              const float* __restrict__ W_ih,
              const float* __restrict__ W_hh,
              const float* __restrict__ b_ih,
              const float* __restrict__ b_hh,
              const float* __restrict__ W_out,
              const float* __restrict__ b_out,
              float* __restrict__ out)
{
    __shared__ __align__(16) _Float16 A_[2][16][LDA];
    __shared__ float hs_f[ROWS][HH];
    __shared__ float lg[ROWS][NC];

    const int tid = threadIdx.x;
    const int w   = tid >> 6;
    const int l   = tid & 63;
    const int c   = l & 15;          // A row sel / B col / C col
    const int hi  = l >> 4;          // lane quad: k-slice for A/B frags, row-group for C
    const int hi8 = hi * 8;
    const int u   = w * 16 + c;      // hidden unit for this lane's gates
    const int r0  = blockIdx.x * ROWS;

    // ---- B fragments (weights), fp16, register-resident ----
    // frag f -> (gate g, kstep s): 0..2:(r,s) 3..5:(z,s) 6..7:(nh,0/1) 8:(nx,2)
    f16x8 Bh[9];
    {
        const int GS[9][2] = {{0,0},{0,1},{0,2},{1,0},{1,1},{1,2},{2,0},{2,1},{3,2}};
        #pragma unroll
        for (int f = 0; f < 9; ++f) {
            const int g = GS[f][0], s = GS[f][1];
            #pragma unroll
            for (int j = 0; j < 8; ++j) {
                const int k = s * 32 + hi8 + j;
                float v = 0.f;
                if (g == 2)      { if (k < 64) v = W_hh[(size_t)(u + 128) * HH + k]; }
                else if (g == 3) { if (k >= 64 && k < 64 + INDIM) v = W_ih[(size_t)(u + 128) * INDIM + (k - 64)]; }
                else {
                    const int ru = u + 64 * g;
                    if (k < 64)              v = W_hh[(size_t)ru * HH + k];
                    else if (k < 64 + INDIM) v = W_ih[(size_t)ru * INDIM + (k - 64)];
                }
                Bh[f][j] = (_Float16)v;
            }
        }
    }
    const float bs0  = b_ih[u]       + b_hh[u];        // r-gate bias
    const float bs1  = b_ih[u + 64]  + b_hh[u + 64];   // z-gate bias
    const float bihn = b_ih[u + 128];                  // n-gate x bias
    const float bhhn = b_hh[u + 128];                  // n-gate h bias (inside r*(...))

    // ---- zero both A buffers (h starts 0; pad cols stay 0) ----
    for (int i = tid; i < 2 * 16 * LDA; i += NTHREADS) ((_Float16*)A_)[i] = (_Float16)0.f;

    // x staging: 16 rows x 28 cols = 448 entries over 256 threads (entry tid, tid+256)
    const int  row0 = tid / INDIM,          col0 = tid % INDIM;          // rows 0..9
    const bool a1   = tid < (ROWS * INDIM - NTHREADS);                   // 192 threads
    const int  e1   = tid + NTHREADS;
    const int  row1 = a1 ? (e1 / INDIM) : 0, col1 = a1 ? (e1 % INDIM) : 0;
    const float* xb0 = x + (size_t)(r0 + row0) * TT * INDIM + col0;
    const float* xb1 = x + (size_t)(r0 + row1) * TT * INDIM + col1;

    // stage x_0
    A_[0][row0][64 + col0] = (_Float16)xb0[0];
    if (a1) A_[0][row1][64 + col1] = (_Float16)xb1[0];
    // prefetch group 0's x: steps 1..8
    float xg0[8], xg1[8];
    #pragma unroll
    for (int k = 0; k < 8; ++k) {
        xg0[k] = xb0[(size_t)(1 + k) * INDIM];
        xg1[k] = a1 ? xb1[(size_t)(1 + k) * INDIM] : 0.f;
    }
    __syncthreads();

    float h[4] = {0.f, 0.f, 0.f, 0.f};   // batch rows 4*hi + i
    const f32x4 z4 = {0.f, 0.f, 0.f, 0.f};
    int p = 0;

    for (int g = 0; g < TT / 8; ++g) {
        // issue next group's x loads (steps 8g+9 .. 8g+16); consumed >= 8 iters later
        float xn0[8], xn1[8];
        #pragma unroll
        for (int k = 0; k < 8; ++k) {
            const int st = 8 * (g + 1) + 1 + k;
            const bool ok = st < TT;
            xn0[k] = ok ? xb0[(size_t)st * INDIM] : 0.f;
            xn1[k] = (ok && a1) ? xb1[(size_t)st * INDIM] : 0.f;
        }

        #pragma unroll
        for (int k = 0; k < 8; ++k) {
            const int t = 8 * g + k;

            const f16x8 af0 = *(const f16x8*)&A_[p][c][hi8];
            const f16x8 af1 = *(const f16x8*)&A_[p][c][32 + hi8];
            const f16x8 af2 = *(const f16x8*)&A_[p][c][64 + hi8];

            // 9 MFMAs; first of each chain consumes the hoisted zero-quad (no re-init)
            f32x4 a0 = MFMA(af0, Bh[0], z4);     // r
            f32x4 a1v = MFMA(af0, Bh[3], z4);    // z
            f32x4 a2 = MFMA(af0, Bh[6], z4);     // n_h
            a0  = MFMA(af1, Bh[1], a0);
            a1v = MFMA(af1, Bh[4], a1v);
            a2  = MFMA(af1, Bh[7], a2);
            a0  = MFMA(af2, Bh[2], a0);
            a1v = MFMA(af2, Bh[5], a1v);
            f32x4 a3 = MFMA(af2, Bh[8], z4);     // n_x

            // gate math fully in-lane: element i = batch row 4*hi + i
            #pragma unroll
            for (int i = 0; i < 4; ++i) {
                const float rg = fsig(a0[i] + bs0);
                const float zg = fsig(a1v[i] + bs1);
                const float ng = ftanh_(a3[i] + bihn + rg * (a2[i] + bhhn));
                h[i] = fmaf(zg, h[i] - ng, ng);      // (1-z)*n + z*h
            }
            // write h_{t+1}: row = 4*hi + i, col u (each (row,col) written by one lane)
            #pragma unroll
            for (int i = 0; i < 4; ++i)
                A_[p ^ 1][4 * hi + i][u] = (_Float16)h[i];
            // write x_{t+1} from the 8-deep prefetch (loads completed long ago)
            if (t + 1 < TT) {
                A_[p ^ 1][row0][64 + col0] = (_Float16)xg0[k];
                if (a1) A_[p ^ 1][row1][64 + col1] = (_Float16)xg1[k];
            }
            lds_barrier();
            p ^= 1;
        }
        #pragma unroll
        for (int k = 0; k < 8; ++k) { xg0[k] = xn0[k]; xg1[k] = xn1[k]; }
    }

    // ---- epilogue: logits + softmax for this block's 16 rows ----
    #pragma unroll
    for (int i = 0; i < 4; ++i) hs_f[4 * hi + i][u] = h[i];
    __syncthreads();
    if (tid < ROWS * NC) {
        const int rr = tid / NC, cc = tid % NC;
        float s = b_out[cc];
        const float* wo = W_out + (size_t)cc * HH;
        #pragma unroll
        for (int j = 0; j < HH; ++j) s = fmaf(wo[j], hs_f[rr][j], s);
        lg[rr][cc] = s;
    }
    __syncthreads();
    if (tid < ROWS) {
        float mx = -1e30f;
        #pragma unroll
        for (int cc = 0; cc < NC; ++cc) mx = fmaxf(mx, lg[tid][cc]);
        float e[NC]; float ssum = 0.f;
        #pragma unroll
        for (int cc = 0; cc < NC; ++cc) { e[cc] = __expf(lg[tid][cc] - mx); ssum += e[cc]; }
        const float inv = 1.f / ssum;
        float* op = out + (size_t)(r0 + tid) * NC;
        #pragma unroll
        for (int cc = 0; cc < NC; ++cc) op[cc] = e[cc] * inv;
    }
}

extern "C" void kernel_launch(void* const* d_in, const int* in_sizes, int n_in,
                              void* d_out, int out_size, void* d_ws, size_t ws_size,
                              hipStream_t stream) {
    const float* x     = (const float*)d_in[0];
    const float* W_ih  = (const float*)d_in[1];
    const float* W_hh  = (const float*)d_in[2];
    const float* b_ih  = (const float*)d_in[3];
    const float* b_hh  = (const float*)d_in[4];
    const float* W_out = (const float*)d_in[5];
    const float* b_out = (const float*)d_in[6];
    (void)in_sizes; (void)n_in; (void)d_ws; (void)ws_size; (void)out_size;

    gru_mfma<<<BB / ROWS, NTHREADS, 0, stream>>>(x, W_ih, W_hh, b_ih, b_hh,
                                                 W_out, b_out, (float*)d_out);
}

// Round 10
// 199.273 us; speedup vs baseline: 2.7382x; 1.1219x over previous
//
#include <hip/hip_runtime.h>

#define BB     2048
#define TT     512
#define INDIM  28
#define HH     64
#define NC     10
#define ROWS   16
#define NTHREADS 256
#define LDH    104   // halfs per H row: 208 B stride -> 16B-aligned rows, proven 2-way-max banking

typedef __attribute__((ext_vector_type(8))) _Float16 f16x8;
typedef __attribute__((ext_vector_type(4))) _Float16 f16x4;
typedef __attribute__((ext_vector_type(4))) float     f32x4;

__device__ __forceinline__ float frcp(float v)  { return __builtin_amdgcn_rcpf(v); }
__device__ __forceinline__ float fsig(float v)  { return frcp(1.f + __expf(-v)); }
__device__ __forceinline__ float ftanh_(float v){ return fmaf(-2.f, frcp(1.f + __expf(2.f*v)), 1.f); }

#define MFMA(A_, B_, C_) __builtin_amdgcn_mfma_f32_16x16x32_f16((A_), (B_), (C_), 0, 0, 0)

// LDS-only barrier: orders our ds_writes (lgkmcnt(0)) then syncs. Does NOT drain vmcnt,
// so the 8-deep x global-load ring stays in flight across step boundaries.
__device__ __forceinline__ void lds_barrier() {
    asm volatile("s_waitcnt lgkmcnt(0)" ::: "memory");
    __builtin_amdgcn_s_barrier();
}

// Operand-swapped pure-fp16 design: D = W · [h|x]^T  (A = weights, B = h/x tile).
// The weight fragment registers and the LDS h-read pattern are BIT-IDENTICAL to the
// verified round-9 kernel (A-frag[row c][k hi8+j] == old B-frag values == W[w16+c][k];
// h B-frag[k hi8+j][col c] == H[c][s*32+hi8..] == old af reads). Only the C layout
// moves: lane (hi,c) now holds gates for units w16+4hi+0..3 of batch row c, so
//  - h-write = ONE ds_write_b64 (4 consecutive units at row c), was 4 strided b16
//  - x never touches LDS: per-lane float4 ring (slot k reloaded each step for t+8,
//    compile-time indices), fp16-converted at use (overlaps MFMA issue)
//  - biases ride in as MFMA C-init vectors (elem i <-> unit w16+4hi+i)
extern "C" __global__ __launch_bounds__(NTHREADS, 1)
void gru_mfma(const float* __restrict__ x,
              const float* __restrict__ W_ih,
              const float* __restrict__ W_hh,
              const float* __restrict__ b_ih,
              const float* __restrict__ b_hh,
              const float* __restrict__ W_out,
              const float* __restrict__ b_out,
              float* __restrict__ out)
{
    __shared__ __align__(16) _Float16 H_[2][16][LDH];
    __shared__ float hs_f[ROWS][HH];
    __shared__ float lg[ROWS][NC];

    const int tid = threadIdx.x;
    const int w   = tid >> 6;
    const int l   = tid & 63;
    const int c   = l & 15;          // batch row this lane owns / B col / A row
    const int hi  = l >> 4;          // lane quad: k-slice for frags, unit-group for C
    const int hi8 = hi * 8;
    const int u   = w * 16 + c;      // unit index for the weight A-frags
    const int u0  = w * 16 + 4 * hi; // first unit of this lane's 4 C regs
    const int r0  = blockIdx.x * ROWS;

    // ---- weight fragments (A-operand), fp16, register-resident (same data as r3-r9) ----
    // frag f -> (gate g, kstep s): 0..2:(r,s) 3..5:(z,s) 6..7:(nh,0/1) 8:(nx,2)
    f16x8 Bh[9];
    {
        const int GS[9][2] = {{0,0},{0,1},{0,2},{1,0},{1,1},{1,2},{2,0},{2,1},{3,2}};
        #pragma unroll
        for (int f = 0; f < 9; ++f) {
            const int g = GS[f][0], s = GS[f][1];
            #pragma unroll
            for (int j = 0; j < 8; ++j) {
                const int k = s * 32 + hi8 + j;
                float v = 0.f;
                if (g == 2)      { if (k < 64) v = W_hh[(size_t)(u + 128) * HH + k]; }
                else if (g == 3) { if (k >= 64 && k < 64 + INDIM) v = W_ih[(size_t)(u + 128) * INDIM + (k - 64)]; }
                else {
                    const int ru = u + 64 * g;
                    if (k < 64)              v = W_hh[(size_t)ru * HH + k];
                    else if (k < 64 + INDIM) v = W_ih[(size_t)ru * INDIM + (k - 64)];
                }
                Bh[f][j] = (_Float16)v;
            }
        }
    }
    // bias vectors as accumulator inits: elem i <-> unit u0+i
    f32x4 bv_r, bv_z, bv_nh, bv_nx;
    #pragma unroll
    for (int i = 0; i < 4; ++i) {
        bv_r[i]  = b_ih[u0 + i]       + b_hh[u0 + i];
        bv_z[i]  = b_ih[u0 + i + 64]  + b_hh[u0 + i + 64];
        bv_nh[i] = b_hh[u0 + i + 128];     // n-gate h bias (inside r*(...))
        bv_nx[i] = b_ih[u0 + i + 128];     // n-gate x bias
    }

    // ---- zero both H buffers (h starts at 0) ----
    for (int i = tid; i < 2 * 16 * LDH; i += NTHREADS) ((_Float16*)H_)[i] = (_Float16)0.f;

    // ---- x ring: lane (hi,c) owns x[row c][dims hi8..hi8+7], 8 steps deep ----
    const float* xlane = x + (size_t)(r0 + c) * (size_t)TT * INDIM + hi8;
    const float4 zf4 = {0.f, 0.f, 0.f, 0.f};
    float4 xa[8], xb[8];                 // slot k holds x_{8g+k}; hi==3: dims 28..31 = 0
    #pragma unroll
    for (int k = 0; k < 8; ++k) {
        xa[k] = *(const float4*)(xlane + (size_t)k * INDIM);
        xb[k] = (hi < 3) ? *(const float4*)(xlane + (size_t)k * INDIM + 4) : zf4;
    }
    __syncthreads();

    float h[4] = {0.f, 0.f, 0.f, 0.f};   // h for (row c, units u0..u0+3)
    int p = 0;

    for (int g = 0; g < TT / 8; ++g) {
        #pragma unroll
        for (int k = 0; k < 8; ++k) {
            const int t = 8 * g + k;

            // x B-frag from the ring (loaded 8 steps ago; cvt overlaps MFMA issue)
            f16x8 xf;
            {
                const float v[8] = {xa[k].x, xa[k].y, xa[k].z, xa[k].w,
                                    xb[k].x, xb[k].y, xb[k].z, xb[k].w};
                #pragma unroll
                for (int j = 0; j < 8; ++j) xf[j] = (_Float16)v[j];
            }
            // h B-frags from LDS (identical pattern to round 9)
            const f16x8 bf0 = *(const f16x8*)&H_[p][c][hi8];
            const f16x8 bf1 = *(const f16x8*)&H_[p][c][32 + hi8];

            // 9 MFMAs, bias-initialized accumulators
            f32x4 a0 = MFMA(Bh[0], bf0, bv_r);
            f32x4 a1 = MFMA(Bh[3], bf0, bv_z);
            f32x4 a2 = MFMA(Bh[6], bf0, bv_nh);
            a0 = MFMA(Bh[1], bf1, a0);
            a1 = MFMA(Bh[4], bf1, a1);
            a2 = MFMA(Bh[7], bf1, a2);
            a0 = MFMA(Bh[2], xf, a0);
            a1 = MFMA(Bh[5], xf, a1);
            f32x4 a3 = MFMA(Bh[8], xf, bv_nx);

            // gate math fully in-lane: elem i = unit u0+i, row c
            f16x4 hv;
            #pragma unroll
            for (int i = 0; i < 4; ++i) {
                const float rg = fsig(a0[i]);
                const float zg = fsig(a1[i]);
                const float ng = ftanh_(fmaf(rg, a2[i], a3[i]));
                h[i] = fmaf(zg, h[i] - ng, ng);      // (1-z)*n + z*h
                hv[i] = (_Float16)h[i];
            }
            // ONE packed write: H[row c][units u0..u0+3]
            *(f16x4*)&H_[p ^ 1][c][u0] = hv;

            // reload ring slot k for step t+8 (stays in flight across the barrier)
            if (t + 8 < TT) {
                xa[k] = *(const float4*)(xlane + (size_t)(t + 8) * INDIM);
                if (hi < 3) xb[k] = *(const float4*)(xlane + (size_t)(t + 8) * INDIM + 4);
            }
            lds_barrier();
            p ^= 1;
        }
    }

    // ---- epilogue: logits + softmax for this block's 16 rows ----
    #pragma unroll
    for (int i = 0; i < 4; ++i) hs_f[c][u0 + i] = h[i];
    __syncthreads();
    if (tid < ROWS * NC) {
        const int rr = tid / NC, cc = tid % NC;
        float s = b_out[cc];
        const float* wo = W_out + (size_t)cc * HH;
        #pragma unroll
        for (int j = 0; j < HH; ++j) s = fmaf(wo[j], hs_f[rr][j], s);
        lg[rr][cc] = s;
    }
    __syncthreads();
    if (tid < ROWS) {
        float mx = -1e30f;
        #pragma unroll
        for (int cc = 0; cc < NC; ++cc) mx = fmaxf(mx, lg[tid][cc]);
        float e[NC]; float ssum = 0.f;
        #pragma unroll
        for (int cc = 0; cc < NC; ++cc) { e[cc] = __expf(lg[tid][cc] - mx); ssum += e[cc]; }
        const float inv = 1.f / ssum;
        float* op = out + (size_t)(r0 + tid) * NC;
        #pragma unroll
        for (int cc = 0; cc < NC; ++cc) op[cc] = e[cc] * inv;
    }
}

extern "C" void kernel_launch(void* const* d_in, const int* in_sizes, int n_in,
                              void* d_out, int out_size, void* d_ws, size_t ws_size,
                              hipStream_t stream) {
    const float* x     = (const float*)d_in[0];
    const float* W_ih  = (const float*)d_in[1];
    const float* W_hh  = (const float*)d_in[2];
    const float* b_ih  = (const float*)d_in[3];
    const float* b_hh  = (const float*)d_in[4];
    const float* W_out = (const float*)d_in[5];
    const float* b_out = (const float*)d_in[6];
    (void)in_sizes; (void)n_in; (void)d_ws; (void)ws_size; (void)out_size;

    gru_mfma<<<BB / ROWS, NTHREADS, 0, stream>>>(x, W_ih, W_hh, b_ih, b_hh,
                                                 W_out, b_out, (float*)d_out);
}